// Round 2
// baseline (12556.816 us; speedup 1.0000x reference)
//
#include <hip/hip_runtime.h>
#include <math.h>

// Problem constants
static constexpr int B_ = 128;
static constexpr int T_ = 64;
static constexpr int E_ = 2048;
static constexpr int H_ = 1024;
static constexpr int R_ = 8;
static constexpr int H3_ = 3 * H_;  // 3072

// ---------------------------------------------------------------------------
__global__ __launch_bounds__(256) void zero_kernel(float* __restrict__ p, int n) {
    int i = blockIdx.x * 256 + threadIdx.x;
    if (i < n) p[i] = 0.0f;
}

// ---------------------------------------------------------------------------
// Phase 1 (chunked): C[m, j] = sum_k enc[row(m), k] * W[j*ldw + k] + bias[j]
// m in [0, B*Tc): b = m >> tcshift, tc = m & (Tc-1), row = b*T + t0 + tc.
// N = 3072 (=3H), K = 2048 (=E). 128x128 tile, BK=16, 256 thr, 8x8/thread.
// ---------------------------------------------------------------------------
__global__ __launch_bounds__(256) void gemm_bias(
    const float* __restrict__ X, int t0, int tcshift,
    const float* __restrict__ W, int ldw,
    const float* __restrict__ bias, float* __restrict__ C, int K)
{
    const int n0 = blockIdx.x * 128;
    const int m0 = blockIdx.y * 128;
    __shared__ float As[16][132];
    __shared__ float Bs[16][132];
    const int tid = threadIdx.x;
    const int tx = tid & 15, ty = tid >> 4;
    const int tcmask = (1 << tcshift) - 1;

    float acc[8][8] = {};

    for (int k0 = 0; k0 < K; k0 += 16) {
#pragma unroll
        for (int cc = 0; cc < 2; ++cc) {
            int c = tid + cc * 256;          // 512 float4 chunks: 128 rows x 4
            int i = c >> 2, kb = (c & 3) * 4;
            int m = m0 + i;
            int srow = (m >> tcshift) * T_ + t0 + (m & tcmask);
            const float4 va = *(const float4*)(X + (size_t)srow * K + k0 + kb);
            As[kb + 0][i] = va.x; As[kb + 1][i] = va.y;
            As[kb + 2][i] = va.z; As[kb + 3][i] = va.w;
            const float4 vb = *(const float4*)(W + (size_t)(n0 + i) * ldw + k0 + kb);
            Bs[kb + 0][i] = vb.x; Bs[kb + 1][i] = vb.y;
            Bs[kb + 2][i] = vb.z; Bs[kb + 3][i] = vb.w;
        }
        __syncthreads();
#pragma unroll
        for (int kk = 0; kk < 16; ++kk) {
            float a[8], b[8];
            const float4* ap = (const float4*)&As[kk][ty * 8];
            const float4* bp = (const float4*)&Bs[kk][tx * 8];
            float4 a0 = ap[0], a1 = ap[1];
            float4 b0 = bp[0], b1 = bp[1];
            a[0]=a0.x; a[1]=a0.y; a[2]=a0.z; a[3]=a0.w;
            a[4]=a1.x; a[5]=a1.y; a[6]=a1.z; a[7]=a1.w;
            b[0]=b0.x; b[1]=b0.y; b[2]=b0.z; b[3]=b0.w;
            b[4]=b1.x; b[5]=b1.y; b[6]=b1.z; b[7]=b1.w;
#pragma unroll
            for (int p = 0; p < 8; ++p)
#pragma unroll
                for (int q = 0; q < 8; ++q)
                    acc[p][q] += a[p] * b[q];
        }
        __syncthreads();
    }

#pragma unroll
    for (int p = 0; p < 8; ++p) {
        int m = m0 + ty * 8 + p;
#pragma unroll
        for (int q = 0; q < 8; ++q) {
            int n = n0 + tx * 8 + q;
            C[(size_t)m * H3_ + n] = acc[p][q] + bias[n];
        }
    }
}

// ---------------------------------------------------------------------------
// Per-step GEMMs, with gather of input rows from the state A_old.
// gridDim = (24, 10): x = n-tile (N=3072), y = group
//   gy=0: giS = A[b,adr]  @ ws_ih[:,E:]^T     (M=128)
//   gy=1: ghS = A[b,spk]  @ ws_hh^T           (M=128)
//   gy=2: giA = A[b,spk]  @ wa_ih[:,E:]^T     (M=128)
//   gy=3: ghA = A[b,adr]  @ wa_hh^T           (M=128)
//   gy=4..9: ghO rows (b*6+j) = A[b,other_j] @ wo_hh^T  (M=768)
// G row layout: [0,128) giS | [128,256) ghS | [256,384) giA | [384,512) ghA |
//               [512,1280) ghO
// ---------------------------------------------------------------------------
__global__ __launch_bounds__(256) void step_gemm(
    const float* __restrict__ Aold, const int* __restrict__ dig, int t,
    const float* __restrict__ ws_ih, const float* __restrict__ ws_hh,
    const float* __restrict__ wa_ih, const float* __restrict__ wa_hh,
    const float* __restrict__ wo_hh, float* __restrict__ G)
{
    const int n0 = blockIdx.x * 128;
    const int gy = blockIdx.y;
    __shared__ float As[16][132];
    __shared__ float Bs[16][132];
    __shared__ int rowoff[128];
    const int tid = threadIdx.x;

    const float* W;
    int ldw;
    float* Cout;
    if (gy == 0)      { W = ws_ih + E_; ldw = 3072; Cout = G; }
    else if (gy == 1) { W = ws_hh;      ldw = 1024; Cout = G + (size_t)128 * H3_; }
    else if (gy == 2) { W = wa_ih + E_; ldw = 3072; Cout = G + (size_t)256 * H3_; }
    else if (gy == 3) { W = wa_hh;      ldw = 1024; Cout = G + (size_t)384 * H3_; }
    else              { W = wo_hh;      ldw = 1024; Cout = G + (size_t)(512 + (gy - 4) * 128) * H3_; }

    if (tid < 128) {
        int role;
        if (gy < 4) {
            int b = tid;
            int spk = dig[(b * T_ + t) * 2 + 0];
            int adr = dig[(b * T_ + t) * 2 + 1];
            role = (gy == 0 || gy == 3) ? adr : spk;
            rowoff[tid] = (b * R_ + role) * H_;
        } else {
            int mo = (gy - 4) * 128 + tid;
            int b = mo / 6;
            int j = mo - b * 6;
            if (b < B_) {
                int spk = dig[(b * T_ + t) * 2 + 0];
                int adr = dig[(b * T_ + t) * 2 + 1];
                int cnt = 0; role = 0;
                for (int r = 0; r < R_; ++r) {
                    if (r != spk && r != adr) {
                        if (cnt == j) { role = r; break; }
                        ++cnt;
                    }
                }
                rowoff[tid] = (b * R_ + role) * H_;
            } else {
                rowoff[tid] = 0;   // padding rows (mo >= 768 never happens; safe)
            }
        }
    }
    __syncthreads();

    const int tx = tid & 15, ty = tid >> 4;
    float acc[8][8] = {};

    for (int k0 = 0; k0 < 1024; k0 += 16) {
#pragma unroll
        for (int cc = 0; cc < 2; ++cc) {
            int c = tid + cc * 256;
            int i = c >> 2, kb = (c & 3) * 4;
            const float4 va = *(const float4*)(Aold + rowoff[i] + k0 + kb);
            As[kb + 0][i] = va.x; As[kb + 1][i] = va.y;
            As[kb + 2][i] = va.z; As[kb + 3][i] = va.w;
            const float4 vb = *(const float4*)(W + (size_t)(n0 + i) * ldw + k0 + kb);
            Bs[kb + 0][i] = vb.x; Bs[kb + 1][i] = vb.y;
            Bs[kb + 2][i] = vb.z; Bs[kb + 3][i] = vb.w;
        }
        __syncthreads();
#pragma unroll
        for (int kk = 0; kk < 16; ++kk) {
            float a[8], b[8];
            const float4* ap = (const float4*)&As[kk][ty * 8];
            const float4* bp = (const float4*)&Bs[kk][tx * 8];
            float4 a0 = ap[0], a1 = ap[1];
            float4 b0 = bp[0], b1 = bp[1];
            a[0]=a0.x; a[1]=a0.y; a[2]=a0.z; a[3]=a0.w;
            a[4]=a1.x; a[5]=a1.y; a[6]=a1.z; a[7]=a1.w;
            b[0]=b0.x; b[1]=b0.y; b[2]=b0.z; b[3]=b0.w;
            b[4]=b1.x; b[5]=b1.y; b[6]=b1.z; b[7]=b1.w;
#pragma unroll
            for (int p = 0; p < 8; ++p)
#pragma unroll
                for (int q = 0; q < 8; ++q)
                    acc[p][q] += a[p] * b[q];
        }
        __syncthreads();
    }

#pragma unroll
    for (int p = 0; p < 8; ++p) {
        int m = ty * 8 + p;
#pragma unroll
        for (int q = 0; q < 8; ++q) {
            int n = n0 + tx * 8 + q;
            Cout[(size_t)m * H3_ + n] = acc[p][q];
        }
    }
}

// ---------------------------------------------------------------------------
// Gate kernel: combine precomputed gi (GIX/GIA/GIO, chunk-local index tloc),
// per-step partials (G), hh biases, prev state -> new state. Block per (b,r).
// ---------------------------------------------------------------------------
__global__ __launch_bounds__(256) void gate_kernel(
    const float* __restrict__ Aold, float* __restrict__ Anew,
    const int* __restrict__ dig, int t, int tloc, int Tc,
    const float* __restrict__ GIX, const float* __restrict__ GIA,
    const float* __restrict__ GIO, const float* __restrict__ G,
    const float* __restrict__ ws_bhh, const float* __restrict__ wa_bhh,
    const float* __restrict__ wo_bhh)
{
    const int blk = blockIdx.x;       // b*R + r
    const int b = blk >> 3, r = blk & 7;
    const int spk = dig[(b * T_ + t) * 2 + 0];
    const int adr = dig[(b * T_ + t) * 2 + 1];
    const size_t gi_row = (size_t)(b * Tc + tloc) * H3_;

    const float* gi_pre;
    const float* gi_add;   // may be null (others)
    const float* gh;
    const float* bhh;
    if (r == spk) {
        gi_pre = GIX + gi_row;
        gi_add = G + (size_t)b * H3_;
        gh     = G + (size_t)(128 + b) * H3_;
        bhh    = ws_bhh;
    } else if (r == adr) {
        gi_pre = GIA + gi_row;
        gi_add = G + (size_t)(256 + b) * H3_;
        gh     = G + (size_t)(384 + b) * H3_;
        bhh    = wa_bhh;
    } else {
        int oidx = r - (spk < r ? 1 : 0) - (adr < r ? 1 : 0);
        gi_pre = GIO + gi_row;
        gi_add = nullptr;
        gh     = G + (size_t)(512 + b * 6 + oidx) * H3_;
        bhh    = wo_bhh;
    }

    const size_t hoff = (size_t)(b * R_ + r) * H_;
    for (int i = threadIdx.x; i < H_; i += 256) {
        float gir = gi_pre[i];
        float giz = gi_pre[H_ + i];
        float gin = gi_pre[2 * H_ + i];
        if (gi_add) {
            gir += gi_add[i];
            giz += gi_add[H_ + i];
            gin += gi_add[2 * H_ + i];
        }
        float ghr = gh[i]          + bhh[i];
        float ghz = gh[H_ + i]     + bhh[H_ + i];
        float ghn = gh[2 * H_ + i] + bhh[2 * H_ + i];

        float rg = 1.0f / (1.0f + __expf(-(gir + ghr)));
        float zg = 1.0f / (1.0f + __expf(-(giz + ghz)));
        float ng = tanhf(gin + rg * ghn);
        float h  = Aold[hoff + i];
        Anew[hoff + i] = (1.0f - zg) * ng + zg * h;
    }
}

// ---------------------------------------------------------------------------
extern "C" void kernel_launch(void* const* d_in, const int* in_sizes, int n_in,
                              void* d_out, int out_size, void* d_ws, size_t ws_size,
                              hipStream_t stream) {
    const float* enc    = (const float*)d_in[0];
    const int*   dig    = (const int*)d_in[1];
    const float* ws_ih  = (const float*)d_in[2];
    const float* ws_hh  = (const float*)d_in[3];
    const float* ws_bih = (const float*)d_in[4];
    const float* ws_bhh = (const float*)d_in[5];
    const float* wa_ih  = (const float*)d_in[6];
    const float* wa_hh  = (const float*)d_in[7];
    const float* wa_bih = (const float*)d_in[8];
    const float* wa_bhh = (const float*)d_in[9];
    const float* wo_ih  = (const float*)d_in[10];
    const float* wo_hh  = (const float*)d_in[11];
    const float* wo_bih = (const float*)d_in[12];
    const float* wo_bhh = (const float*)d_in[13];

    float* A0 = (float*)d_out;                    // (B, R, H) final output
    float* ws = (float*)d_ws;

    // Fixed-cost workspace pieces (floats):
    const size_t A_sz = (size_t)B_ * R_ * H_;     // 1,048,576
    const size_t G_sz = (size_t)1280 * H3_;       // 3,932,160
    // Per-timestep GI cost (3 weight sets): 3 * B * H3 floats.
    const size_t per_t = (size_t)3 * B_ * H3_;    // 1,179,648 floats / step

    // Largest power-of-two chunk Tc <= 64 that fits ws_size.
    int Tc = 64;
    while (Tc > 1 &&
           (A_sz + G_sz + per_t * (size_t)Tc) * sizeof(float) > ws_size)
        Tc >>= 1;
    int tcshift = 0;
    while ((1 << tcshift) < Tc) ++tcshift;

    const size_t GI_sz = (size_t)B_ * Tc * H3_;   // per weight set, chunk-local
    float* GIX = ws;
    float* GIA = GIX + GI_sz;
    float* GIO = GIA + GI_sz;
    float* A1  = GIO + GI_sz;                     // (B, R, H) ping-pong
    float* G   = A1 + A_sz;                       // 1280 x 3072 partials

    dim3 blk(256);

    // Initial state = zeros (harness poisons d_out with 0xAA).
    zero_kernel<<<dim3((int)((A_sz + 255) / 256)), blk, 0, stream>>>(A0, (int)A_sz);

    float* Aold = A0;
    float* Anew = A1;
    for (int t0 = 0; t0 < T_; t0 += Tc) {
        // Phase 1 (chunk): input-side gate contributions for Tc timesteps.
        dim3 g1(H3_ / 128, (B_ * Tc) / 128);
        gemm_bias<<<g1, blk, 0, stream>>>(enc, t0, tcshift, ws_ih, 3072, ws_bih, GIX, E_);
        gemm_bias<<<g1, blk, 0, stream>>>(enc, t0, tcshift, wa_ih, 3072, wa_bih, GIA, E_);
        gemm_bias<<<g1, blk, 0, stream>>>(enc, t0, tcshift, wo_ih, 2048, wo_bih, GIO, E_);

        // Phase 2: sequential recurrence within the chunk.
        for (int t = t0; t < t0 + Tc; ++t) {
            step_gemm<<<dim3(H3_ / 128, 10), blk, 0, stream>>>(
                Aold, dig, t, ws_ih, ws_hh, wa_ih, wa_hh, wo_hh, G);
            gate_kernel<<<dim3(B_ * R_), blk, 0, stream>>>(
                Aold, Anew, dig, t, t - t0, Tc, GIX, GIA, GIO, G,
                ws_bhh, wa_bhh, wo_bhh);
            float* tmp = Aold; Aold = Anew; Anew = tmp;
        }
    }
    // T_ = 64 total steps (even): final state was written into A0 == d_out.
}

// Round 3
// 3164.540 us; speedup vs baseline: 3.9680x; 3.9680x over previous
//
#include <hip/hip_runtime.h>
#include <math.h>
#include <stdint.h>

// Problem constants
static constexpr int B_ = 128;
static constexpr int T_ = 64;
static constexpr int E_ = 2048;
static constexpr int H_ = 1024;
static constexpr int R_ = 8;
static constexpr int H3_ = 3 * H_;  // 3072

typedef unsigned short u16;
typedef __attribute__((ext_vector_type(8))) __bf16 bf16x8;
typedef __attribute__((ext_vector_type(4))) float f32x4;

__device__ __forceinline__ u16 f2bf(float f) {
    uint32_t x = __float_as_uint(f);
    x += 0x7fffu + ((x >> 16) & 1u);      // round-to-nearest-even
    return (u16)(x >> 16);
}
__device__ __forceinline__ float bf2f(u16 u) {
    return __uint_as_float(((uint32_t)u) << 16);
}

// async global->LDS, 16B per lane; LDS dest = wave-uniform base + lane*16
__device__ __forceinline__ void async_cp16(const u16* g, u16* l) {
    auto* g1 = (const __attribute__((address_space(1))) u16*)g;
    auto* l3 = (__attribute__((address_space(3))) u16*)(uintptr_t)l;
    __builtin_amdgcn_global_load_lds((const __attribute__((address_space(1))) void*)g1,
                                     (__attribute__((address_space(3))) void*)l3,
                                     16, 0, 0);
}

// ---------------------------------------------------------------------------
__global__ __launch_bounds__(256) void zero_kernel(float* __restrict__ p, int n) {
    int i = blockIdx.x * 256 + threadIdx.x;
    if (i < n) p[i] = 0.0f;
}

// fp32 -> bf16 pack: dst[r*cols+c] = bf16(src[r*src_ld + col0 + c])
__global__ __launch_bounds__(256) void conv_bf(
    const float* __restrict__ src, int src_ld, int col0, int cols,
    u16* __restrict__ dst, int total4)
{
    int i4 = blockIdx.x * 256 + threadIdx.x;
    if (i4 >= total4) return;
    int i = i4 * 4;
    int r = i / cols, c = i - r * cols;
    const float4 v = *(const float4*)(src + (size_t)r * src_ld + col0 + c);
    ushort4 o;
    o.x = f2bf(v.x); o.y = f2bf(v.y); o.z = f2bf(v.z); o.w = f2bf(v.w);
    *(ushort4*)(dst + i) = o;
}

// ---------------------------------------------------------------------------
// Phase 1 MFMA GEMM: C[m,n] = bf16( sum_k X[row(m),k]*W[n,k] + bias[n] )
// X = enc_bf (ld E_), W packed bf16 [3072 x 2048], C = GI bf16 (ld H3_).
// 128x128 tile, BK=32, 256 thr (4 waves, 2x2 of 64x64), 16x16x32 MFMA.
// ---------------------------------------------------------------------------
__global__ __launch_bounds__(256) void mfma_p1(
    const u16* __restrict__ X, int t0, int tcshift,
    const u16* __restrict__ W, const float* __restrict__ bias,
    u16* __restrict__ C)
{
    __shared__ u16 As[128 * 32];
    __shared__ u16 Bs[128 * 32];
    __shared__ int rowoff[128];
    const int tid = threadIdx.x;
    const int n0 = blockIdx.x * 128;
    const int m0 = blockIdx.y * 128;
    const int tcmask = (1 << tcshift) - 1;
    if (tid < 128) {
        int m = m0 + tid;
        rowoff[tid] = ((m >> tcshift) * T_ + t0 + (m & tcmask)) * E_;
    }
    __syncthreads();

    const int lane = tid & 63;
    const int wm = ((tid >> 6) & 1) * 64;
    const int wn = (tid >> 7) * 64;
    const int fr = lane & 15;            // fragment row (m for A, n for B)
    const int kq = (lane >> 4) * 8;      // k-quad offset
    const int wbase = (tid & 192) * 8;   // wave-uniform LDS chunk base (elems)

    f32x4 acc[4][4] = {};

    for (int k0 = 0; k0 < E_; k0 += 32) {
#pragma unroll
        for (int p = 0; p < 2; ++p) {
            int c = p * 256 + tid;
            int row = c >> 2, kc = (c & 3) * 8;
            async_cp16(X + rowoff[row] + k0 + kc, &As[p * 2048 + wbase]);
            async_cp16(W + (size_t)(n0 + row) * E_ + k0 + kc, &Bs[p * 2048 + wbase]);
        }
        __syncthreads();
        bf16x8 a[4], b[4];
#pragma unroll
        for (int i = 0; i < 4; ++i) {
            a[i] = *(const bf16x8*)&As[(wm + i * 16 + fr) * 32 + kq];
            b[i] = *(const bf16x8*)&Bs[(wn + i * 16 + fr) * 32 + kq];
        }
#pragma unroll
        for (int mt = 0; mt < 4; ++mt)
#pragma unroll
            for (int nt = 0; nt < 4; ++nt)
                acc[mt][nt] = __builtin_amdgcn_mfma_f32_16x16x32_bf16(
                    a[mt], b[nt], acc[mt][nt], 0, 0, 0);
        __syncthreads();
    }

#pragma unroll
    for (int mt = 0; mt < 4; ++mt)
#pragma unroll
        for (int nt = 0; nt < 4; ++nt) {
            int n = n0 + wn + nt * 16 + fr;
            float bs = bias[n];
#pragma unroll
            for (int i = 0; i < 4; ++i) {
                int m = m0 + wm + mt * 16 + (lane >> 4) * 4 + i;
                C[(size_t)m * H3_ + n] = f2bf(acc[mt][nt][i] + bs);
            }
        }
}

// ---------------------------------------------------------------------------
// Per-step MFMA GEMM over gathered state rows. grid (24, 10).
//   gy=0: giS = A[b,adr] @ Whsi^T | gy=1: ghS = A[b,spk] @ Whs^T
//   gy=2: giA = A[b,spk] @ Whai^T | gy=3: ghA = A[b,adr] @ Wha^T
//   gy=4..9: ghO = A[b,oth_j] @ Who^T  (768 rows)
// G row layout: [0,128) giS | [128,256) ghS | [256,384) giA | [384,512) ghA |
//               [512,1280) ghO. All K = H_ = 1024.
// ---------------------------------------------------------------------------
__global__ __launch_bounds__(256) void mfma_step(
    const u16* __restrict__ Abf, const int* __restrict__ dig, int t,
    const u16* __restrict__ Whsi, const u16* __restrict__ Whs,
    const u16* __restrict__ Whai, const u16* __restrict__ Wha,
    const u16* __restrict__ Who, float* __restrict__ G)
{
    __shared__ u16 As[128 * 32];
    __shared__ u16 Bs[128 * 32];
    __shared__ int rowoff[128];
    const int tid = threadIdx.x;
    const int n0 = blockIdx.x * 128;
    const int gy = blockIdx.y;

    const u16* W;
    float* Cout;
    if (gy == 0)      { W = Whsi; Cout = G; }
    else if (gy == 1) { W = Whs;  Cout = G + (size_t)128 * H3_; }
    else if (gy == 2) { W = Whai; Cout = G + (size_t)256 * H3_; }
    else if (gy == 3) { W = Wha;  Cout = G + (size_t)384 * H3_; }
    else              { W = Who;  Cout = G + (size_t)(512 + (gy - 4) * 128) * H3_; }

    if (tid < 128) {
        int role, b;
        if (gy < 4) {
            b = tid;
            int spk = dig[(b * T_ + t) * 2 + 0];
            int adr = dig[(b * T_ + t) * 2 + 1];
            role = (gy == 0 || gy == 3) ? adr : spk;
        } else {
            int mo = (gy - 4) * 128 + tid;
            b = mo / 6;
            int j = mo - b * 6;
            int spk = dig[(b * T_ + t) * 2 + 0];
            int adr = dig[(b * T_ + t) * 2 + 1];
            int cnt = 0; role = 0;
            for (int r = 0; r < R_; ++r) {
                if (r != spk && r != adr) {
                    if (cnt == j) { role = r; break; }
                    ++cnt;
                }
            }
        }
        rowoff[tid] = (b * R_ + role) * H_;
    }
    __syncthreads();

    const int lane = tid & 63;
    const int wm = ((tid >> 6) & 1) * 64;
    const int wn = (tid >> 7) * 64;
    const int fr = lane & 15;
    const int kq = (lane >> 4) * 8;
    const int wbase = (tid & 192) * 8;

    f32x4 acc[4][4] = {};

    for (int k0 = 0; k0 < H_; k0 += 32) {
#pragma unroll
        for (int p = 0; p < 2; ++p) {
            int c = p * 256 + tid;
            int row = c >> 2, kc = (c & 3) * 8;
            async_cp16(Abf + rowoff[row] + k0 + kc, &As[p * 2048 + wbase]);
            async_cp16(W + (size_t)(n0 + row) * H_ + k0 + kc, &Bs[p * 2048 + wbase]);
        }
        __syncthreads();
        bf16x8 a[4], b[4];
#pragma unroll
        for (int i = 0; i < 4; ++i) {
            a[i] = *(const bf16x8*)&As[(wm + i * 16 + fr) * 32 + kq];
            b[i] = *(const bf16x8*)&Bs[(wn + i * 16 + fr) * 32 + kq];
        }
#pragma unroll
        for (int mt = 0; mt < 4; ++mt)
#pragma unroll
            for (int nt = 0; nt < 4; ++nt)
                acc[mt][nt] = __builtin_amdgcn_mfma_f32_16x16x32_bf16(
                    a[mt], b[nt], acc[mt][nt], 0, 0, 0);
        __syncthreads();
    }

#pragma unroll
    for (int mt = 0; mt < 4; ++mt)
#pragma unroll
        for (int nt = 0; nt < 4; ++nt) {
            int n = n0 + wn + nt * 16 + fr;
#pragma unroll
            for (int i = 0; i < 4; ++i) {
                int m = wm + mt * 16 + (lane >> 4) * 4 + i;
                Cout[(size_t)m * H3_ + n] = acc[mt][nt][i];
            }
        }
}

// ---------------------------------------------------------------------------
// Gate kernel. Block per (b, r). Writes fp32 state (Anew) + bf16 copy (Abf).
// ---------------------------------------------------------------------------
__global__ __launch_bounds__(256) void gate_kernel(
    const float* __restrict__ Aold, float* __restrict__ Anew,
    u16* __restrict__ Abf,
    const int* __restrict__ dig, int t, int tloc, int Tc,
    const u16* __restrict__ GIX, const u16* __restrict__ GIA,
    const u16* __restrict__ GIO, const float* __restrict__ G,
    const float* __restrict__ ws_bhh, const float* __restrict__ wa_bhh,
    const float* __restrict__ wo_bhh)
{
    const int blk = blockIdx.x;       // b*R + r
    const int b = blk >> 3, r = blk & 7;
    const int spk = dig[(b * T_ + t) * 2 + 0];
    const int adr = dig[(b * T_ + t) * 2 + 1];
    const size_t gi_row = (size_t)(b * Tc + tloc) * H3_;

    const u16* gi_pre;
    const float* gi_add;   // may be null (others)
    const float* gh;
    const float* bhh;
    if (r == spk) {
        gi_pre = GIX + gi_row;
        gi_add = G + (size_t)b * H3_;
        gh     = G + (size_t)(128 + b) * H3_;
        bhh    = ws_bhh;
    } else if (r == adr) {
        gi_pre = GIA + gi_row;
        gi_add = G + (size_t)(256 + b) * H3_;
        gh     = G + (size_t)(384 + b) * H3_;
        bhh    = wa_bhh;
    } else {
        int oidx = r - (spk < r ? 1 : 0) - (adr < r ? 1 : 0);
        gi_pre = GIO + gi_row;
        gi_add = nullptr;
        gh     = G + (size_t)(512 + b * 6 + oidx) * H3_;
        bhh    = wo_bhh;
    }

    const size_t hoff = (size_t)(b * R_ + r) * H_;
    for (int i = threadIdx.x; i < H_; i += 256) {
        float gir = bf2f(gi_pre[i]);
        float giz = bf2f(gi_pre[H_ + i]);
        float gin = bf2f(gi_pre[2 * H_ + i]);
        if (gi_add) {
            gir += gi_add[i];
            giz += gi_add[H_ + i];
            gin += gi_add[2 * H_ + i];
        }
        float ghr = gh[i]          + bhh[i];
        float ghz = gh[H_ + i]     + bhh[H_ + i];
        float ghn = gh[2 * H_ + i] + bhh[2 * H_ + i];

        float rg = 1.0f / (1.0f + __expf(-(gir + ghr)));
        float zg = 1.0f / (1.0f + __expf(-(giz + ghz)));
        float ng = tanhf(gin + rg * ghn);
        float h  = Aold[hoff + i];
        float o  = (1.0f - zg) * ng + zg * h;
        Anew[hoff + i] = o;
        Abf[hoff + i]  = f2bf(o);
    }
}

// ---------------------------------------------------------------------------
extern "C" void kernel_launch(void* const* d_in, const int* in_sizes, int n_in,
                              void* d_out, int out_size, void* d_ws, size_t ws_size,
                              hipStream_t stream) {
    const float* enc    = (const float*)d_in[0];
    const int*   dig    = (const int*)d_in[1];
    const float* ws_ih  = (const float*)d_in[2];
    const float* ws_hh  = (const float*)d_in[3];
    const float* ws_bih = (const float*)d_in[4];
    const float* ws_bhh = (const float*)d_in[5];
    const float* wa_ih  = (const float*)d_in[6];
    const float* wa_hh  = (const float*)d_in[7];
    const float* wa_bih = (const float*)d_in[8];
    const float* wa_bhh = (const float*)d_in[9];
    const float* wo_ih  = (const float*)d_in[10];
    const float* wo_hh  = (const float*)d_in[11];
    const float* wo_bih = (const float*)d_in[12];
    const float* wo_bhh = (const float*)d_in[13];

    float* A0 = (float*)d_out;                    // (B, R, H) final output

    // ---- workspace layout (bytes) ----
    char* p = (char*)d_ws;
    auto take = [&](size_t bytes) { char* q = p; p += (bytes + 255) & ~(size_t)255; return q; };
    u16*   enc_bf = (u16*)  take((size_t)B_ * T_ * E_ * 2);          // 33.6 MB
    u16*   W1s    = (u16*)  take((size_t)H3_ * E_ * 2);              // 12.6 MB
    u16*   W1a    = (u16*)  take((size_t)H3_ * E_ * 2);
    u16*   W1o    = (u16*)  take((size_t)H3_ * E_ * 2);
    u16*   Whsi   = (u16*)  take((size_t)H3_ * H_ * 2);              // 6.3 MB
    u16*   Whai   = (u16*)  take((size_t)H3_ * H_ * 2);
    u16*   Whs    = (u16*)  take((size_t)H3_ * H_ * 2);
    u16*   Wha    = (u16*)  take((size_t)H3_ * H_ * 2);
    u16*   Who    = (u16*)  take((size_t)H3_ * H_ * 2);
    u16*   Abf    = (u16*)  take((size_t)B_ * R_ * H_ * 2);          // 2 MB
    float* A1     = (float*)take((size_t)B_ * R_ * H_ * 4);          // 4 MB
    float* G      = (float*)take((size_t)1280 * H3_ * 4);            // 15.7 MB
    size_t fixed = (size_t)(p - (char*)d_ws);

    // chunk size: largest power-of-two Tc <= 64 fitting GI (3 sets, bf16)
    const size_t per_t = (size_t)3 * B_ * H3_ * 2;                   // 2.36 MB/step
    int Tc = 64;
    while (Tc > 1 && fixed + per_t * (size_t)Tc > ws_size) Tc >>= 1;
    int tcshift = 0;
    while ((1 << tcshift) < Tc) ++tcshift;
    const size_t GI_elems = (size_t)B_ * Tc * H3_;
    u16* GIX = (u16*)take(GI_elems * 2);
    u16* GIA = (u16*)take(GI_elems * 2);
    u16* GIO = (u16*)take(GI_elems * 2);

    dim3 blk(256);
    const size_t A_sz = (size_t)B_ * R_ * H_;

    // zero fp32 state (d_out) and bf16 state copy
    zero_kernel<<<dim3((int)((A_sz + 255) / 256)), blk, 0, stream>>>(A0, (int)A_sz);
    zero_kernel<<<dim3((int)((A_sz / 2 + 255) / 256)), blk, 0, stream>>>((float*)Abf, (int)(A_sz / 2));

    // ---- one-time bf16 conversions ----
    {
        int t4;
        t4 = B_ * T_ * E_ / 4;
        conv_bf<<<dim3((t4 + 255) / 256), blk, 0, stream>>>(enc, E_, 0, E_, enc_bf, t4);
        t4 = H3_ * E_ / 4;
        conv_bf<<<dim3((t4 + 255) / 256), blk, 0, stream>>>(ws_ih, E_ + H_, 0, E_, W1s, t4);
        conv_bf<<<dim3((t4 + 255) / 256), blk, 0, stream>>>(wa_ih, E_ + H_, 0, E_, W1a, t4);
        conv_bf<<<dim3((t4 + 255) / 256), blk, 0, stream>>>(wo_ih, E_, 0, E_, W1o, t4);
        t4 = H3_ * H_ / 4;
        conv_bf<<<dim3((t4 + 255) / 256), blk, 0, stream>>>(ws_ih, E_ + H_, E_, H_, Whsi, t4);
        conv_bf<<<dim3((t4 + 255) / 256), blk, 0, stream>>>(wa_ih, E_ + H_, E_, H_, Whai, t4);
        conv_bf<<<dim3((t4 + 255) / 256), blk, 0, stream>>>(ws_hh, H_, 0, H_, Whs, t4);
        conv_bf<<<dim3((t4 + 255) / 256), blk, 0, stream>>>(wa_hh, H_, 0, H_, Wha, t4);
        conv_bf<<<dim3((t4 + 255) / 256), blk, 0, stream>>>(wo_hh, H_, 0, H_, Who, t4);
    }

    float* Aold = A0;
    float* Anew = A1;
    for (int t0 = 0; t0 < T_; t0 += Tc) {
        // Phase 1 (chunk): input-side gate contributions, bf16 MFMA.
        dim3 g1(H3_ / 128, (B_ * Tc) / 128);
        mfma_p1<<<g1, blk, 0, stream>>>(enc_bf, t0, tcshift, W1s, ws_bih, GIX);
        mfma_p1<<<g1, blk, 0, stream>>>(enc_bf, t0, tcshift, W1a, wa_bih, GIA);
        mfma_p1<<<g1, blk, 0, stream>>>(enc_bf, t0, tcshift, W1o, wo_bih, GIO);

        // Phase 2: sequential recurrence within the chunk.
        for (int t = t0; t < t0 + Tc; ++t) {
            mfma_step<<<dim3(H3_ / 128, 10), blk, 0, stream>>>(
                Abf, dig, t, Whsi, Whs, Whai, Wha, Who, G);
            gate_kernel<<<dim3(B_ * R_), blk, 0, stream>>>(
                Aold, Anew, Abf, dig, t, t - t0, Tc, GIX, GIA, GIO, G,
                ws_bhh, wa_bhh, wo_bhh);
            float* tmp = Aold; Aold = Anew; Anew = tmp;
        }
    }
    // T_ = 64 total steps (even): final state lands in A0 == d_out.
}